// Round 15
// baseline (159.515 us; speedup 1.0000x reference)
//
#include <hip/hip_runtime.h>
#include <hip/hip_bf16.h>
#include <stdint.h>

#define D_EMB 128
#define D_NLP 768
#define TR 16              // tile rows
#define NKC 12             // k64 iterations

typedef __attribute__((ext_vector_type(8))) short bf16x8;
typedef __attribute__((ext_vector_type(4))) float f32x4;
typedef __attribute__((ext_vector_type(8))) unsigned short u16x8;

__device__ __forceinline__ unsigned short f2bf(float f) {
  unsigned u = __builtin_bit_cast(unsigned, f);
  u += 0x7fffu + ((u >> 16) & 1u);   // RTNE (NaN-free inputs)
  return (unsigned short)(u >> 16);
}

__device__ __forceinline__ bf16x8 pack8(const float4& a, const float4& b) {
  u16x8 v;
  v[0] = __builtin_bit_cast(unsigned short, __float2bfloat16(a.x));
  v[1] = __builtin_bit_cast(unsigned short, __float2bfloat16(a.y));
  v[2] = __builtin_bit_cast(unsigned short, __float2bfloat16(a.z));
  v[3] = __builtin_bit_cast(unsigned short, __float2bfloat16(a.w));
  v[4] = __builtin_bit_cast(unsigned short, __float2bfloat16(b.x));
  v[5] = __builtin_bit_cast(unsigned short, __float2bfloat16(b.y));
  v[6] = __builtin_bit_cast(unsigned short, __float2bfloat16(b.z));
  v[7] = __builtin_bit_cast(unsigned short, __float2bfloat16(b.w));
  return __builtin_bit_cast(bf16x8, v);
}

// ---- kernel W: w0 (128x768 f32) -> bf16, pre-swizzled per 64-k chunk (B path).
__global__ void kw(const float* __restrict__ w0, unsigned short* __restrict__ w0s,
                   int* __restrict__ mn) {
  if (blockIdx.x == 0 && threadIdx.x == 0) mn[0] = 0x7fffffff;
  int t = blockIdx.x * 256 + threadIdx.x;       // 12288 units
  if (t >= (D_EMB * D_NLP) / 8) return;
  int u = t & 7, row = (t >> 3) & 127, kc = t >> 10;
  const float4* src = (const float4*)(w0 + (size_t)row * D_NLP + kc * 64 + ((u ^ (row & 7)) * 8));
  float4 v0 = src[0], v1 = src[1];
  u16x8 o;
  o[0] = f2bf(v0.x); o[1] = f2bf(v0.y); o[2] = f2bf(v0.z); o[3] = f2bf(v0.w);
  o[4] = f2bf(v1.x); o[5] = f2bf(v1.y); o[6] = f2bf(v1.z); o[7] = f2bf(v1.w);
  *(u16x8*)(w0s + (size_t)t * 8) = o;
}

// ---- kernel M: mn = min_e max(ei[0][e], ei[1][e])  (R11 config)
__global__ void km(const int* __restrict__ ei, int E, int* __restrict__ mn) {
  int t = blockIdx.x * blockDim.x + threadIdx.x;
  int stride = gridDim.x * blockDim.x;
  int m = 0x7fffffff;
  for (int e = t; e < E; e += stride) {
    int a = ei[e], b = ei[E + e];
    int q = a > b ? a : b;
    m = q < m ? q : m;
  }
  #pragma unroll
  for (int off = 32; off; off >>= 1) {
    int o = __shfl_xor(m, off);
    m = o < m ? o : m;
  }
  if ((threadIdx.x & 63) == 0) atomicMin(mn, m);
}

// ---- kernel C: 16-row tiles, 1KB-granule A staging.
// Each global_load_lds = ONE aligned contiguous 1KB block of one z0 row
// (swizzle = lane permutation within the KB; still fully coalesced).
// A ring-2 of 256-float chunks (2x16KB); B ring-3 of 64-k chunks (3x16KB,
// pre-swizzled w0s). Counted vmcnt per derived schedule; 80KB -> 2 blocks/CU.
// 4 waves = 4 col-groups of 32; sv combined via tiny LDS reduce; z-dot fused.
__global__ __launch_bounds__(256) void kc(
    const float* __restrict__ z0, const float* __restrict__ z,
    const unsigned short* __restrict__ w0s, const float* __restrict__ w1,
    const float* __restrict__ prelu_a, float* __restrict__ sv,
    float* __restrict__ ta, float* __restrict__ tb, int N) {
  extern __shared__ char smem[];
  float* Al = (float*)smem;                              // 2 x 16 x 256f = 32KB
  unsigned short* Bl = (unsigned short*)(smem + 32768);  // 3 x 8192 = 48KB

  const int tid = threadIdx.x;
  const int lane = tid & 63;
  const int wave = tid >> 6;       // col-group 0..3
  const int kg = lane >> 4;
  const int col = lane & 15;
  const int asw = col & 7;
  const int r0 = blockIdx.x * TR;

  // A sources: wave w stages rows w*4+p; one instr = that row's contiguous 1KB
  // (lane^c permutation inside the KB matches the ds_read-side XOR).
  const float* aSrc[4];
  #pragma unroll
  for (int p = 0; p < 4; ++p) {
    int rl = wave * 4 + p;
    int rg = min(r0 + rl, N - 1);
    aSrc[p] = z0 + (size_t)rg * D_NLP + ((lane ^ (rl & 7)) * 4);
  }

  auto stageA = [&](int g, int buf) {     // g = 256-float chunk index 0..2
    #pragma unroll
    for (int p = 0; p < 4; ++p) {
      __builtin_amdgcn_global_load_lds(
          (const __attribute__((address_space(1))) void*)(aSrc[p] + g * 256),
          (__attribute__((address_space(3))) void*)&Al[buf * 4096 + (wave * 4 + p) * 256],
          16, 0, 0);
    }
  };
  auto stageB = [&](int t, int buf) {
    const unsigned short* g = w0s + (size_t)t * (D_EMB * 64) + (size_t)tid * 8;
    #pragma unroll
    for (int p = 0; p < 4; ++p) {
      __builtin_amdgcn_global_load_lds(
          (const __attribute__((address_space(1))) void*)(g + p * 256 * 8),
          (__attribute__((address_space(3))) void*)&Bl[buf * 8192 + (wave * 64 + p * 256) * 8],
          16, 0, 0);
    }
  };

  f32x4 acc[2];
  acc[0] = (f32x4){0.f, 0.f, 0.f, 0.f};
  acc[1] = (f32x4){0.f, 0.f, 0.f, 0.f};

  // prologue order A0,B0,A1,B1 -> wait(0)=vmcnt(8) keeps A1,B1 flying
  stageA(0, 0);
  stageB(0, 0);
  stageA(1, 1);
  stageB(1, 1);

#define KITER(T, VM) do {                                                     \
    asm volatile("s_waitcnt vmcnt(" #VM ")" ::: "memory");                    \
    __builtin_amdgcn_s_barrier();                                             \
    if ((T) + 2 < NKC) stageB((T) + 2, ((T) + 2) % 3);                        \
    if ((T) == 4) stageA(2, 0);                                               \
    __builtin_amdgcn_sched_barrier(0);                                        \
    const float* Ab = Al + (((T) >> 2) & 1) * 4096;                           \
    const unsigned short* Bbuf = Bl + ((T) % 3) * 8192;                       \
    _Pragma("unroll")                                                         \
    for (int ks = 0; ks < 2; ++ks) {                                          \
      int u0 = ((T) & 3) * 16 + ks * 8 + kg * 2;                              \
      float4 lo = *(const float4*)&Ab[col * 256 + ((u0)     ^ asw) * 4];      \
      float4 hi = *(const float4*)&Ab[col * 256 + ((u0 + 1) ^ asw) * 4];      \
      bf16x8 af = pack8(lo, hi);                                              \
      _Pragma("unroll")                                                       \
      for (int bc = 0; bc < 2; ++bc) {                                        \
        int brow = wave * 32 + bc * 16 + col;                                 \
        bf16x8 bfr = *(const bf16x8*)&Bbuf[(brow * 8 + ((ks * 4 + kg) ^ (brow & 7))) * 8]; \
        acc[bc] = __builtin_amdgcn_mfma_f32_16x16x32_bf16(af, bfr, acc[bc], 0, 0, 0); \
      }                                                                       \
    }                                                                         \
  } while (0)

  KITER(0, 8);  KITER(1, 4);  KITER(2, 4);  KITER(3, 4);
  KITER(4, 4);  KITER(5, 8);  KITER(6, 8);  KITER(7, 4);
  KITER(8, 4);  KITER(9, 4);  KITER(10, 4); KITER(11, 0);
#undef KITER

  // sv: prelu * w1c over this wave's 32 cols, 16-lane reduce, cross-wave LDS add
  float ap = prelu_a[0];
  float ssum[4] = {0.f, 0.f, 0.f, 0.f};
  #pragma unroll
  for (int bc = 0; bc < 2; ++bc) {
    float wc = w1[2 * D_EMB + wave * 32 + bc * 16 + col];
    #pragma unroll
    for (int i = 0; i < 4; ++i) {
      float h = acc[bc][i];
      float x = h >= 0.f ? h : ap * h;
      ssum[i] += x * wc;
    }
  }
  #pragma unroll
  for (int off = 1; off < 16; off <<= 1) {
    #pragma unroll
    for (int i = 0; i < 4; ++i) ssum[i] += __shfl_xor(ssum[i], off);
  }
  __syncthreads();                 // A buffers dead -> reuse as reduce scratch
  float* red = Al;                 // red[4][16]
  if (col == 0) {
    #pragma unroll
    for (int i = 0; i < 4; ++i) red[wave * 16 + kg * 4 + i] = ssum[i];
  }
  __syncthreads();
  if (tid < TR) {
    int r = r0 + tid;
    if (r < N) sv[r] = red[tid] + red[16 + tid] + red[32 + tid] + red[48 + tid];
  }

  // fused z-dot: wave w covers rows w*4+kg; 16 lanes (col) x 8 floats each
  {
    int zr = r0 + wave * 4 + kg;
    int rg = min(zr, N - 1);
    const float4* zp = (const float4*)(z + (size_t)rg * D_EMB + col * 8);
    float4 z0v = zp[0], z1v = zp[1];
    const float4* wa4 = (const float4*)(w1 + col * 8);
    const float4* wb4 = (const float4*)(w1 + D_EMB + col * 8);
    float4 wa0 = wa4[0], wa1 = wa4[1];
    float4 wb0 = wb4[0], wb1 = wb4[1];
    float pa = z0v.x * wa0.x + z0v.y * wa0.y + z0v.z * wa0.z + z0v.w * wa0.w
             + z1v.x * wa1.x + z1v.y * wa1.y + z1v.z * wa1.z + z1v.w * wa1.w;
    float pb = z0v.x * wb0.x + z0v.y * wb0.y + z0v.z * wb0.z + z0v.w * wb0.w
             + z1v.x * wb1.x + z1v.y * wb1.y + z1v.z * wb1.z + z1v.w * wb1.w;
    pa += __shfl_xor(pa, 1); pb += __shfl_xor(pb, 1);
    pa += __shfl_xor(pa, 2); pb += __shfl_xor(pb, 2);
    pa += __shfl_xor(pa, 4); pb += __shfl_xor(pb, 4);
    pa += __shfl_xor(pa, 8); pb += __shfl_xor(pb, 8);
    if (col == 0 && zr < N) { ta[zr] = pa; tb[zr] = pb; }
  }
}

// ---- kernel D: per-edge gather + add
__global__ void kd(const int* __restrict__ ei, const int* __restrict__ mn,
                   const float* __restrict__ ta, const float* __restrict__ tb,
                   const float* __restrict__ sv, const float* __restrict__ b1,
                   float* __restrict__ out, int E) {
  int e = blockIdx.x * blockDim.x + threadIdx.x;
  if (e >= E) return;
  int i0 = ei[e], i1 = ei[E + e];
  int q = (i0 > i1 ? i0 : i1) - mn[0];
  out[e] = ta[i0] + tb[i1] + sv[q] + b1[0];
}

extern "C" void kernel_launch(void* const* d_in, const int* in_sizes, int n_in,
                              void* d_out, int out_size, void* d_ws, size_t ws_size,
                              hipStream_t stream) {
  const float* z  = (const float*)d_in[0];
  const float* z0 = (const float*)d_in[1];
  const int*   ei = (const int*)d_in[2];
  const float* w0 = (const float*)d_in[3];
  const float* pa = (const float*)d_in[4];
  const float* w1 = (const float*)d_in[5];
  const float* b1 = (const float*)d_in[6];
  float* out = (float*)d_out;
  const int N = in_sizes[0] / D_EMB;
  const int E = in_sizes[2] / 2;

  // ws: [0,4) mn | [256,+192KB) w0s bf16 pre-swizzled | ta[N], tb[N], sv[N]
  char* ws = (char*)d_ws;
  int* mn = (int*)ws;
  unsigned short* w0s = (unsigned short*)(ws + 256);
  float* ta = (float*)(ws + 256 + 196608);
  float* tb = ta + N;
  float* sv = tb + N;

  hipFuncSetAttribute((const void*)kc,
                      hipFuncAttributeMaxDynamicSharedMemorySize, 81920);

  kw<<<(D_EMB * D_NLP / 8 + 255) / 256, 256, 0, stream>>>(w0, w0s, mn);
  km<<<256, 256, 0, stream>>>(ei, E, mn);
  kc<<<(N + TR - 1) / TR, 256, 81920, stream>>>(z0, z, w0s, w1, pa, sv, ta, tb, N);
  kd<<<(E + 255) / 256, 256, 0, stream>>>(ei, mn, ta, tb, sv, b1, out, E);
}

// Round 16
// 146.858 us; speedup vs baseline: 1.0862x; 1.0862x over previous
//
#include <hip/hip_runtime.h>
#include <hip/hip_bf16.h>
#include <stdint.h>

#define D_EMB 128
#define D_NLP 768
#define BM 64
#define BK 64
#define NKC (D_NLP / BK)   // 12 k-chunks

typedef __attribute__((ext_vector_type(8))) short bf16x8;
typedef __attribute__((ext_vector_type(4))) float f32x4;
typedef __attribute__((ext_vector_type(8))) unsigned short u16x8;

__device__ __forceinline__ unsigned short f2bf(float f) {
  unsigned u = __builtin_bit_cast(unsigned, f);
  u += 0x7fffu + ((u >> 16) & 1u);   // RTNE (NaN-free inputs)
  return (unsigned short)(u >> 16);
}

__device__ __forceinline__ bf16x8 pack8(const float4& a, const float4& b) {
  u16x8 v;
  v[0] = __builtin_bit_cast(unsigned short, __float2bfloat16(a.x));
  v[1] = __builtin_bit_cast(unsigned short, __float2bfloat16(a.y));
  v[2] = __builtin_bit_cast(unsigned short, __float2bfloat16(a.z));
  v[3] = __builtin_bit_cast(unsigned short, __float2bfloat16(a.w));
  v[4] = __builtin_bit_cast(unsigned short, __float2bfloat16(b.x));
  v[5] = __builtin_bit_cast(unsigned short, __float2bfloat16(b.y));
  v[6] = __builtin_bit_cast(unsigned short, __float2bfloat16(b.z));
  v[7] = __builtin_bit_cast(unsigned short, __float2bfloat16(b.w));
  return __builtin_bit_cast(bf16x8, v);
}

// ---- kernel W: w0 (128x768 f32) -> bf16, pre-swizzled per 64-k chunk (B path).
__global__ void kw(const float* __restrict__ w0, unsigned short* __restrict__ w0s,
                   int* __restrict__ mn) {
  if (blockIdx.x == 0 && threadIdx.x == 0) mn[0] = 0x7fffffff;
  int t = blockIdx.x * 256 + threadIdx.x;       // 12288 units
  if (t >= (D_EMB * D_NLP) / 8) return;
  int u = t & 7, row = (t >> 3) & 127, kc = t >> 10;
  const float4* src = (const float4*)(w0 + (size_t)row * D_NLP + kc * 64 + ((u ^ (row & 7)) * 8));
  float4 v0 = src[0], v1 = src[1];
  u16x8 o;
  o[0] = f2bf(v0.x); o[1] = f2bf(v0.y); o[2] = f2bf(v0.z); o[3] = f2bf(v0.w);
  o[4] = f2bf(v1.x); o[5] = f2bf(v1.y); o[6] = f2bf(v1.z); o[7] = f2bf(v1.w);
  *(u16x8*)(w0s + (size_t)t * 8) = o;
}

// ---- kernel M: mn = min_e max(ei[0][e], ei[1][e])
__global__ void km(const int* __restrict__ ei, int E, int* __restrict__ mn) {
  int t = blockIdx.x * blockDim.x + threadIdx.x;
  int stride = gridDim.x * blockDim.x;
  int m = 0x7fffffff;
  for (int e = t; e < E; e += stride) {
    int a = ei[e], b = ei[E + e];
    int q = a > b ? a : b;
    m = q < m ? q : m;
  }
  #pragma unroll
  for (int off = 32; off; off >>= 1) {
    int o = __shfl_xor(m, off);
    m = o < m ? o : m;
  }
  if ((threadIdx.x & 63) == 0) atomicMin(mn, m);
}

// ---- kernel C: R11 pipeline body, MULTI-TILE per block (kdiag-proven shape).
// Each block processes `reps` tiles strided by gridDim.x: per tile a full
// drain -> prologue -> 12 counted-vmcnt iters -> epilogues. kdiag<2> measured
// this shape (sans epilogues) at 56.5 us/z0-pass vs 105 for 1-tile blocks:
// block-turnover frequency is the lever, not cross-tile pipelining.
// Wraparound recompute of <=3 tail tiles is idempotent (same values written).
__global__ __launch_bounds__(256) void kc(
    const float* __restrict__ z0, const float* __restrict__ z,
    const unsigned short* __restrict__ w0s, const float* __restrict__ w1,
    const float* __restrict__ prelu_a, float* __restrict__ sv,
    float* __restrict__ ta, float* __restrict__ tb, int N, int NT, int reps) {
  extern __shared__ char smem[];
  float* Al = (float*)smem;                              // 3 x 64 x 64f = 48KB
  unsigned short* Bl = (unsigned short*)(smem + 49152);  // 2 x 8192 = 32KB

  const int tid = threadIdx.x;
  const int lane = tid & 63;
  const int wave = tid >> 6;
  const int kg = lane >> 4;
  const int col = lane & 15;
  const int s16 = lane & 15;
  const int hl = lane >> 4;
  const int arow_l = (wave * 16 + col) * 64;
  const int asw = col & 7;

  const float ap = prelu_a[0];
  float wcf[8];
  #pragma unroll
  for (int c = 0; c < 8; ++c) wcf[c] = w1[2 * D_EMB + c * 16 + col];

  for (int rep = 0, tile = blockIdx.x; rep < reps; ++rep, tile += gridDim.x) {
    int tt = tile;
    if (tt >= NT) tt -= NT;                    // idempotent tail recompute
    const int r0 = tt * BM;
    const int myrow = r0 + wave * 16 + col;
    const int arow_g = min(myrow, N - 1);

    const float* aSrc[4];
    #pragma unroll
    for (int p = 0; p < 4; ++p) {
      int rl = p * 4 + hl;
      int rg = min(r0 + wave * 16 + rl, N - 1);
      int cu = s16 ^ (rl & 7);
      aSrc[p] = z0 + (size_t)rg * D_NLP + cu * 4;
    }

    auto stageA = [&](int t, int buf) {
      #pragma unroll
      for (int p = 0; p < 4; ++p) {
        __builtin_amdgcn_global_load_lds(
            (const __attribute__((address_space(1))) void*)(aSrc[p] + t * BK),
            (__attribute__((address_space(3))) void*)&Al[buf * 4096 + (wave * 16 + p * 4) * 64],
            16, 0, 0);
      }
    };
    auto stageB = [&](int t, int buf) {
      const unsigned short* g = w0s + (size_t)t * (D_EMB * BK) + (size_t)tid * 8;
      #pragma unroll
      for (int p = 0; p < 4; ++p) {
        __builtin_amdgcn_global_load_lds(
            (const __attribute__((address_space(1))) void*)(g + p * 256 * 8),
            (__attribute__((address_space(3))) void*)&Bl[buf * 8192 + (wave * 64 + p * 256) * 8],
            16, 0, 0);
      }
    };

    f32x4 acc[8];
    #pragma unroll
    for (int c = 0; c < 8; ++c) acc[c] = (f32x4){0.f, 0.f, 0.f, 0.f};

    stageB(0, 0);
    stageA(0, 0);
    stageA(1, 1);

    #pragma unroll
    for (int t = 0; t < NKC; ++t) {
      if (t < NKC - 1) asm volatile("s_waitcnt vmcnt(4)" ::: "memory");
      else             asm volatile("s_waitcnt vmcnt(0)" ::: "memory");
      __builtin_amdgcn_s_barrier();
      if (t + 1 < NKC) stageB(t + 1, (t + 1) & 1);
      if (t + 2 < NKC) stageA(t + 2, (t + 2) % 3);
      __builtin_amdgcn_sched_barrier(0);

      const float* Ab = Al + (t % 3) * 4096;
      const unsigned short* Bbuf = Bl + (t & 1) * 8192;
      #pragma unroll
      for (int ks = 0; ks < 2; ++ks) {
        int u0 = ks * 8 + kg * 2;
        float4 lo = *(const float4*)&Ab[arow_l + ((u0)     ^ asw) * 4];
        float4 hi = *(const float4*)&Ab[arow_l + ((u0 + 1) ^ asw) * 4];
        bf16x8 af = pack8(lo, hi);
        #pragma unroll
        for (int c = 0; c < 8; ++c) {
          int brow = c * 16 + col;
          bf16x8 bfr = *(const bf16x8*)&Bbuf[(brow * 8 + ((ks * 4 + kg) ^ (brow & 7))) * 8];
          acc[c] = __builtin_amdgcn_mfma_f32_16x16x32_bf16(af, bfr, acc[c], 0, 0, 0);
        }
      }
    }

    // epilogue 1: prelu + * w1c, 16-lane-group reduce
    float ssum[4] = {0.f, 0.f, 0.f, 0.f};
    #pragma unroll
    for (int c = 0; c < 8; ++c) {
      #pragma unroll
      for (int i = 0; i < 4; ++i) {
        float h = acc[c][i];
        float x = h >= 0.f ? h : ap * h;
        ssum[i] += x * wcf[c];
      }
    }
    #pragma unroll
    for (int off = 1; off < 16; off <<= 1) {
      #pragma unroll
      for (int i = 0; i < 4; ++i) ssum[i] += __shfl_xor(ssum[i], off);
    }
    if (col == 0) {
      int rbase = r0 + wave * 16 + kg * 4;   // C/D row = (lane>>4)*4 + i
      #pragma unroll
      for (int i = 0; i < 4; ++i) {
        int r = rbase + i;
        if (r < N) sv[r] = ssum[i];
      }
    }

    // epilogue 2 (fused kt): plain loads + use-waits (queue is drained here)
    {
      const float* zp = z + (size_t)arow_g * D_EMB + kg * 32;
      const float4* wa4 = (const float4*)(w1 + kg * 32);
      const float4* wb4 = (const float4*)(w1 + D_EMB + kg * 32);
      float pa = 0.f, pb = 0.f;
      #pragma unroll
      for (int i = 0; i < 8; ++i) {
        float4 zv = ((const float4*)zp)[i];
        float4 wa = wa4[i];
        float4 wb = wb4[i];
        pa += zv.x * wa.x + zv.y * wa.y + zv.z * wa.z + zv.w * wa.w;
        pb += zv.x * wb.x + zv.y * wb.y + zv.z * wb.z + zv.w * wb.w;
      }
      pa += __shfl_xor(pa, 16); pa += __shfl_xor(pa, 32);
      pb += __shfl_xor(pb, 16); pb += __shfl_xor(pb, 32);
      if (kg == 0 && myrow < N) { ta[myrow] = pa; tb[myrow] = pb; }
    }
  }
}

// ---- kernel D: per-edge gather + add
__global__ void kd(const int* __restrict__ ei, const int* __restrict__ mn,
                   const float* __restrict__ ta, const float* __restrict__ tb,
                   const float* __restrict__ sv, const float* __restrict__ b1,
                   float* __restrict__ out, int E) {
  int e = blockIdx.x * blockDim.x + threadIdx.x;
  if (e >= E) return;
  int i0 = ei[e], i1 = ei[E + e];
  int q = (i0 > i1 ? i0 : i1) - mn[0];
  out[e] = ta[i0] + tb[i1] + sv[q] + b1[0];
}

extern "C" void kernel_launch(void* const* d_in, const int* in_sizes, int n_in,
                              void* d_out, int out_size, void* d_ws, size_t ws_size,
                              hipStream_t stream) {
  const float* z  = (const float*)d_in[0];
  const float* z0 = (const float*)d_in[1];
  const int*   ei = (const int*)d_in[2];
  const float* w0 = (const float*)d_in[3];
  const float* pa = (const float*)d_in[4];
  const float* w1 = (const float*)d_in[5];
  const float* b1 = (const float*)d_in[6];
  float* out = (float*)d_out;
  const int N = in_sizes[0] / D_EMB;
  const int E = in_sizes[2] / 2;
  const int NT = (N + BM - 1) / BM;
  const int grid = NT < 522 ? NT : 522;        // 2 blocks/CU resident
  const int reps = (NT + grid - 1) / grid;     // 3 for N=100000

  // ws: [0,4) mn | [256,+192KB) w0s bf16 pre-swizzled | ta[N], tb[N], sv[N]
  char* ws = (char*)d_ws;
  int* mn = (int*)ws;
  unsigned short* w0s = (unsigned short*)(ws + 256);
  float* ta = (float*)(ws + 256 + 196608);
  float* tb = ta + N;
  float* sv = tb + N;

  hipFuncSetAttribute((const void*)kc,
                      hipFuncAttributeMaxDynamicSharedMemorySize, 81920);

  kw<<<(D_EMB * D_NLP / 8 + 255) / 256, 256, 0, stream>>>(w0, w0s, mn);
  km<<<256, 256, 0, stream>>>(ei, E, mn);
  kc<<<grid, 256, 81920, stream>>>(z0, z, w0s, w1, pa, sv, ta, tb, N, NT, reps);
  kd<<<(E + 255) / 256, 256, 0, stream>>>(ei, mn, ta, tb, sv, b1, out, E);
}